// Round 1
// baseline (1070.026 us; speedup 1.0000x reference)
//
#include <hip/hip_runtime.h>
#include <math.h>

// Problem: ClusterisedSelfAttentionNotLearnable
//   X [N=200000, 6] f32, W=linear_mappings [768, 72] f32, centroids [256, 3] f32
//   enc[n] = posenc(X[n]) in R^72; rgb_clusters[n,c,d] = enc[n] . W[c*3+d, :]
//   attn = softmax(X[:, :3] @ centroids^T) over 256 clusters
//   out[n,d] = sum_c attn[n,c] * rgb_clusters[n,c,d]    -> [N, 3] f32
//
// Strategy (round 1): fp32 vector kernel, 1 thread per point.
//   - enc[72] in registers
//   - centroids + W chunk (32 clusters = 27.6 KB) staged in LDS; all lanes read
//     the same LDS address (uniform loop indices) -> broadcast, no conflicts
//   - softmax fused: acc_d += exp(s-m)*dot_d, normalize at end (no attn array)

#define THREADS 256
#define NCLUST  256
#define ENC_DIM 72
#define CHUNK   32                      // clusters staged per LDS tile
#define CHUNK_FLOATS (CHUNK * 3 * ENC_DIM)  // 6912 floats = 27648 B

__global__ __launch_bounds__(THREADS) void rgb_attn_kernel(
    const float* __restrict__ X,
    const float* __restrict__ W,
    const float* __restrict__ cent,
    float* __restrict__ out,
    int N)
{
    __shared__ float sC[NCLUST * 3];
    __shared__ float sW[CHUNK_FLOATS];

    const int tid = threadIdx.x;

    // stage centroids (768 floats)
    for (int i = tid; i < NCLUST * 3; i += THREADS) sC[i] = cent[i];

    const int n = blockIdx.x * THREADS + tid;
    const bool valid = (n < N);

    float x[6];
#pragma unroll
    for (int k = 0; k < 6; ++k) x[k] = valid ? X[n * 6 + k] : 0.0f;

    // positional encoding: enc[d*12 + f] = sin(2^f x_d), enc[d*12 + 6 + f] = cos(2^f x_d)
    float enc[ENC_DIM];
#pragma unroll
    for (int d = 0; d < 6; ++d) {
#pragma unroll
        for (int f = 0; f < 6; ++f) {
            float a = x[d] * (float)(1 << f);
            float s, c;
            sincosf(a, &s, &c);
            enc[d * 12 + f]     = s;
            enc[d * 12 + 6 + f] = c;
        }
    }

    __syncthreads();  // sC ready

    // pass 1: max score (for stable softmax)
    float m = -1e30f;
    for (int c = 0; c < NCLUST; ++c) {
        float s = fmaf(x[0], sC[c * 3 + 0],
                  fmaf(x[1], sC[c * 3 + 1],
                       x[2] * sC[c * 3 + 2]));
        m = fmaxf(m, s);
    }

    float acc0 = 0.0f, acc1 = 0.0f, acc2 = 0.0f, denom = 0.0f;

    for (int ch = 0; ch < NCLUST / CHUNK; ++ch) {
        __syncthreads();  // previous chunk consumers done
        // stage W chunk: rows [ch*CHUNK*3, (ch+1)*CHUNK*3) of [768, 72]
        {
            const float4* gsrc = (const float4*)(W + ch * CHUNK_FLOATS);
            float4* dst = (float4*)sW;
            for (int i = tid; i < CHUNK_FLOATS / 4; i += THREADS) dst[i] = gsrc[i];
        }
        __syncthreads();

#pragma unroll 1
        for (int cc = 0; cc < CHUNK; ++cc) {
            const int c = ch * CHUNK + cc;
            float s = fmaf(x[0], sC[c * 3 + 0],
                      fmaf(x[1], sC[c * 3 + 1],
                           x[2] * sC[c * 3 + 2]));
            float ew = __expf(s - m);

            const float* w = sW + cc * (3 * ENC_DIM);
            float d0 = 0.0f, d1 = 0.0f, d2 = 0.0f;
#pragma unroll
            for (int e = 0; e < ENC_DIM; ++e) {
                float ee = enc[e];
                d0 = fmaf(ee, w[e],               d0);
                d1 = fmaf(ee, w[ENC_DIM + e],     d1);
                d2 = fmaf(ee, w[2 * ENC_DIM + e], d2);
            }
            denom += ew;
            acc0 = fmaf(ew, d0, acc0);
            acc1 = fmaf(ew, d1, acc1);
            acc2 = fmaf(ew, d2, acc2);
        }
    }

    if (valid) {
        float inv = 1.0f / denom;
        out[n * 3 + 0] = acc0 * inv;
        out[n * 3 + 1] = acc1 * inv;
        out[n * 3 + 2] = acc2 * inv;
    }
}

extern "C" void kernel_launch(void* const* d_in, const int* in_sizes, int n_in,
                              void* d_out, int out_size, void* d_ws, size_t ws_size,
                              hipStream_t stream)
{
    const float* X    = (const float*)d_in[0];   // [N, 6]
    const float* W    = (const float*)d_in[1];   // [768, 72]
    const float* cent = (const float*)d_in[2];   // [256, 3]
    float* out = (float*)d_out;                  // [N, 3]

    const int N = in_sizes[0] / 6;
    const int blocks = (N + THREADS - 1) / THREADS;
    rgb_attn_kernel<<<blocks, THREADS, 0, stream>>>(X, W, cent, out, N);
}

// Round 2
// 876.775 us; speedup vs baseline: 1.2204x; 1.2204x over previous
//
#include <hip/hip_runtime.h>
#include <math.h>

// Problem: ClusterisedSelfAttentionNotLearnable
//   X [N=200000, 6] f32, W=linear_mappings [768, 72] f32, centroids [256, 3] f32
//   enc[n] = posenc(X[n]) in R^72; rgb_clusters[n,c,d] = enc[n] . W[c*3+d, :]
//   attn = softmax(X[:, :3] @ centroids^T) over 256 clusters
//   out[n,d] = sum_c attn[n,c] * rgb_clusters[n,c,d]    -> [N, 3] f32
//
// Round 2: W/centroid accesses are wave-uniform -> let the compiler emit
// SCALAR loads (s_load -> SGPR) and consume SGPRs directly in v_fmac.
// This takes the LDS pipe (the R1 bottleneck: ~843us of broadcast
// ds_read_b128 per CU) out of the loop entirely. No __shared__ at all.

#define THREADS 256
#define NCLUST  256
#define ENC_DIM 72

__global__ __launch_bounds__(THREADS) void rgb_attn_kernel(
    const float* __restrict__ X,
    const float* __restrict__ W,
    const float* __restrict__ cent,
    float* __restrict__ out,
    int N)
{
    const int n = blockIdx.x * THREADS + threadIdx.x;
    const bool valid = (n < N);

    float x[6];
#pragma unroll
    for (int k = 0; k < 6; ++k) x[k] = valid ? X[n * 6 + k] : 0.0f;

    // positional encoding: enc[d*12 + f] = sin(2^f x_d), enc[d*12+6+f] = cos(2^f x_d)
    float enc[ENC_DIM];
#pragma unroll
    for (int d = 0; d < 6; ++d) {
#pragma unroll
        for (int f = 0; f < 6; ++f) {
            float a = x[d] * (float)(1 << f);
            float s, c;
            sincosf(a, &s, &c);
            enc[d * 12 + f]     = s;
            enc[d * 12 + 6 + f] = c;
        }
    }

    // pass 1: max score for stable softmax (centroid reads are uniform -> s_load)
    float m = -1e30f;
#pragma unroll 1
    for (int c = 0; c < NCLUST; ++c) {
        float s = fmaf(x[0], cent[c * 3 + 0],
                  fmaf(x[1], cent[c * 3 + 1],
                       x[2] * cent[c * 3 + 2]));
        m = fmaxf(m, s);
    }

    float acc0 = 0.0f, acc1 = 0.0f, acc2 = 0.0f, denom = 0.0f;

#pragma unroll 1
    for (int c = 0; c < NCLUST; ++c) {
        float s = fmaf(x[0], cent[c * 3 + 0],
                  fmaf(x[1], cent[c * 3 + 1],
                       x[2] * cent[c * 3 + 2]));
        float ew = __expf(s - m);

        // W row block for this cluster: 3 rows x 72 -- uniform address ->
        // scalar loads; v_fmac consumes the SGPR operand directly.
        const float* __restrict__ w = W + c * (3 * ENC_DIM);
        float d0 = 0.0f, d1 = 0.0f, d2 = 0.0f;
#pragma unroll
        for (int e = 0; e < ENC_DIM; ++e) {
            float ee = enc[e];
            d0 = fmaf(ee, w[e],               d0);
            d1 = fmaf(ee, w[ENC_DIM + e],     d1);
            d2 = fmaf(ee, w[2 * ENC_DIM + e], d2);
        }
        denom += ew;
        acc0 = fmaf(ew, d0, acc0);
        acc1 = fmaf(ew, d1, acc1);
        acc2 = fmaf(ew, d2, acc2);
    }

    if (valid) {
        float inv = 1.0f / denom;
        out[n * 3 + 0] = acc0 * inv;
        out[n * 3 + 1] = acc1 * inv;
        out[n * 3 + 2] = acc2 * inv;
    }
}

extern "C" void kernel_launch(void* const* d_in, const int* in_sizes, int n_in,
                              void* d_out, int out_size, void* d_ws, size_t ws_size,
                              hipStream_t stream)
{
    const float* X    = (const float*)d_in[0];   // [N, 6]
    const float* W    = (const float*)d_in[1];   // [768, 72]
    const float* cent = (const float*)d_in[2];   // [256, 3]
    float* out = (float*)d_out;                  // [N, 3]

    const int N = in_sizes[0] / 6;
    const int blocks = (N + THREADS - 1) / THREADS;
    rgb_attn_kernel<<<blocks, THREADS, 0, stream>>>(X, W, cent, out, N);
}

// Round 3
// 134.657 us; speedup vs baseline: 7.9463x; 6.5112x over previous
//
#include <hip/hip_runtime.h>
#include <math.h>

// ClusterisedSelfAttentionNotLearnable — MFMA reformulation.
//   out[n,d] = (1/den[n]) * sum_e enc[n,e] * wbar[n,d,e]
//   wbar[n,(d,e)] = sum_c exp(s[n,c]) * W'[c,(d,e)],  W'[c, j=d*72+e] = W[c*3+d, e]
//   -> GEMM [N,256] @ [256,216] bf16 MFMA (16x16x32, K=256 = 8 steps), fused epilogue.
// Prep kernel builds W' as bf16 [224][256] (j-major, k contiguous = B^T layout) in d_ws.

#define NCLUST  256
#define ENC_DIM 72
#define NJ      216
#define NJ_PAD  224
#define M_BLK   128
#define THREADS 256
#define BG_BYTES (NJ_PAD * NCLUST * 2)   // 114688

typedef __attribute__((ext_vector_type(8))) short bfrag_t;   // 8 bf16
typedef __attribute__((ext_vector_type(4))) float cfrag_t;   // 4 f32

static __device__ __forceinline__ unsigned short f2bf(float f) {
    unsigned int u = __float_as_uint(f);
    u += 0x7fffu + ((u >> 16) & 1u);     // RNE
    return (unsigned short)(u >> 16);
}
static __device__ __forceinline__ float bf2f(unsigned short s) {
    return __uint_as_float(((unsigned int)s) << 16);
}

__global__ void prep_kernel(const float* __restrict__ W, unsigned short* __restrict__ Bg) {
    int j = blockIdx.x;    // 0..223 (out-col = d*72+e)
    int c = threadIdx.x;   // 0..255 (cluster = K)
    float v = 0.0f;
    if (j < NJ) {
        int d = j / ENC_DIM;
        int e = j - d * ENC_DIM;
        v = W[(c * 3 + d) * ENC_DIM + e];
    }
    Bg[j * NCLUST + c] = f2bf(v);
}

// LDS strides (bytes): A rows 144 (64 bf16 + 8 pad; pad bytes [128,144) hold denom),
// enc rows 144 (72 bf16), Bl rows 528 (256 bf16 + 8 pad). Total 53760 B -> 3 blocks/CU.
__global__ __launch_bounds__(THREADS, 3) void rgb_attn_mfma(
    const float* __restrict__ X,
    const float* __restrict__ cent,
    const unsigned short* __restrict__ Bg,
    float* __restrict__ out, int N)
{
    __shared__ __align__(16) unsigned short A_lds[M_BLK * 72];    // [128] rows of 144 B
    __shared__ __align__(16) unsigned short enc_lds[M_BLK * 72];  // [128][72] bf16
    __shared__ __align__(16) unsigned short Bl[32 * 264];         // [32][256+8] bf16

    const int tid  = threadIdx.x;
    const int lane = tid & 63;
    const int wv   = tid >> 6;     // wave 0..3
    const int q    = lane >> 4;    // quad 0..3
    const int ln   = lane & 15;

    const int pt  = tid & 127;     // local point this thread produces
    const int h   = tid >> 7;      // half 0/1
    const int gpt = blockIdx.x * M_BLK + pt;
    const int gp  = (gpt < N) ? gpt : (N - 1);

    const float x0 = X[gp * 6 + 0];
    const float x1 = X[gp * 6 + 1];
    const float x2 = X[gp * 6 + 2];

    // ---- positional encoding: thread handles dims [3h, 3h+3) of its point ----
#pragma unroll
    for (int k = 0; k < 3; ++k) {
        const int dd = 3 * h + k;
        const float xv = X[gp * 6 + dd];
        unsigned int sp[3], cp[3];
#pragma unroll
        for (int f = 0; f < 6; f += 2) {
            float s0, c0, s1, c1;
            __sincosf(xv * (float)(1 << f),       &s0, &c0);
            __sincosf(xv * (float)(1 << (f + 1)), &s1, &c1);
            sp[f / 2] = (unsigned int)f2bf(s0) | ((unsigned int)f2bf(s1) << 16);
            cp[f / 2] = (unsigned int)f2bf(c0) | ((unsigned int)f2bf(c1) << 16);
        }
        unsigned int* p = (unsigned int*)((char*)enc_lds + pt * 144 + dd * 24);
        p[0] = sp[0]; p[1] = sp[1]; p[2] = sp[2];
        p[3] = cp[0]; p[4] = cp[1]; p[5] = cp[2];
    }

    // ---- attention production (4 phases of 64 clusters) + A-frag pickup ----
    bfrag_t afrag[2][8];
    float dpart = 0.0f;
#pragma unroll
    for (int p = 0; p < 4; ++p) {
        unsigned int packed[16];
#pragma unroll
        for (int i = 0; i < 32; i += 2) {
            const int c0 = p * 64 + h * 32 + i;
            float s0 = fmaf(x0, cent[c0 * 3 + 0], fmaf(x1, cent[c0 * 3 + 1], x2 * cent[c0 * 3 + 2]));
            float s1 = fmaf(x0, cent[c0 * 3 + 3], fmaf(x1, cent[c0 * 3 + 4], x2 * cent[c0 * 3 + 5]));
            float e0 = __expf(s0), e1 = __expf(s1);
            dpart += e0 + e1;
            packed[i / 2] = (unsigned int)f2bf(e0) | ((unsigned int)f2bf(e1) << 16);
        }
        uint4* dst = (uint4*)((char*)A_lds + pt * 144 + h * 64);
#pragma unroll
        for (int ii = 0; ii < 4; ++ii)
            dst[ii] = make_uint4(packed[ii * 4 + 0], packed[ii * 4 + 1],
                                 packed[ii * 4 + 2], packed[ii * 4 + 3]);
        if (p == 3) {
            float* dn = (float*)((char*)A_lds + pt * 144 + 128);
            dn[h] = dpart;   // unnormalized softmax denominator halves
        }
        __syncthreads();
        // pick up this phase's A-fragments: Ksteps 2p, 2p+1 for our 2 M-tiles
#pragma unroll
        for (int mt = 0; mt < 2; ++mt) {
            const int m = (2 * wv + mt) * 16 + ln;
#pragma unroll
            for (int kw = 0; kw < 2; ++kw)
                afrag[mt][2 * p + kw] =
                    *(const bfrag_t*)((const char*)A_lds + m * 144 + kw * 64 + q * 16);
        }
        __syncthreads();
    }

    // ---- main loop over 7 col-chunks of 32 j-cols ----
    float part0[2][4] = {{0,0,0,0},{0,0,0,0}};
    float part1[2][4] = {{0,0,0,0},{0,0,0,0}};
    float part2[2][4] = {{0,0,0,0},{0,0,0,0}};

#pragma unroll 1
    for (int cc = 0; cc < 7; ++cc) {
        __syncthreads();   // previous chunk's Bl consumers done
        {
            const uint4* src = (const uint4*)(Bg + cc * 32 * NCLUST);
#pragma unroll
            for (int ii = 0; ii < 4; ++ii) {
                const int idx = tid + ii * 256;        // 1024 x 16B = 16 KB
                const int row = idx >> 5, col16 = idx & 31;
                *(uint4*)((char*)Bl + row * 528 + col16 * 16) = src[idx];
            }
        }
        __syncthreads();

#pragma unroll
        for (int ct = 0; ct < 2; ++ct) {
            const int j = cc * 32 + ct * 16 + ln;
            cfrag_t acc0 = {0.f, 0.f, 0.f, 0.f};
            cfrag_t acc1 = {0.f, 0.f, 0.f, 0.f};
#pragma unroll
            for (int ks = 0; ks < 8; ++ks) {
                const bfrag_t b =
                    *(const bfrag_t*)((const char*)Bl + (ct * 16 + ln) * 528 + ks * 64 + q * 16);
                acc0 = __builtin_amdgcn_mfma_f32_16x16x32_bf16(afrag[0][ks], b, acc0, 0, 0, 0);
                acc1 = __builtin_amdgcn_mfma_f32_16x16x32_bf16(afrag[1][ks], b, acc1, 0, 0, 0);
            }
            if (j < NJ) {
                const int d = (j >= 144) ? 2 : ((j >= 72) ? 1 : 0);
                const int e = j - d * ENC_DIM;
#pragma unroll
                for (int mt = 0; mt < 2; ++mt) {
#pragma unroll
                    for (int r = 0; r < 4; ++r) {
                        const int pm = (2 * wv + mt) * 16 + q * 4 + r;  // C row = point
                        const float ev = bf2f(*(const unsigned short*)
                                              ((const char*)enc_lds + pm * 144 + e * 2));
                        const float v = (mt ? acc1[r] : acc0[r]) * ev;
                        if (d == 0)      part0[mt][r] += v;
                        else if (d == 1) part1[mt][r] += v;
                        else             part2[mt][r] += v;
                    }
                }
            }
        }
    }

    // ---- reduce across the 16 n-lanes (butterfly), then write ----
#pragma unroll
    for (int mask = 1; mask <= 8; mask <<= 1) {
#pragma unroll
        for (int mt = 0; mt < 2; ++mt)
#pragma unroll
            for (int r = 0; r < 4; ++r) {
                part0[mt][r] += __shfl_xor(part0[mt][r], mask, 64);
                part1[mt][r] += __shfl_xor(part1[mt][r], mask, 64);
                part2[mt][r] += __shfl_xor(part2[mt][r], mask, 64);
            }
    }
    if (ln == 0) {
#pragma unroll
        for (int mt = 0; mt < 2; ++mt)
#pragma unroll
            for (int r = 0; r < 4; ++r) {
                const int pm = (2 * wv + mt) * 16 + q * 4 + r;
                const int g  = blockIdx.x * M_BLK + pm;
                if (g < N) {
                    const float* dn = (const float*)((const char*)A_lds + pm * 144 + 128);
                    const float inv = 1.0f / (dn[0] + dn[1]);
                    out[g * 3 + 0] = part0[mt][r] * inv;
                    out[g * 3 + 1] = part1[mt][r] * inv;
                    out[g * 3 + 2] = part2[mt][r] * inv;
                }
            }
    }
}

// ---- fallback (correct, slow) if d_ws is too small for Bg ----
__global__ __launch_bounds__(256) void rgb_attn_fallback(
    const float* __restrict__ X, const float* __restrict__ W,
    const float* __restrict__ cent, float* __restrict__ out, int N)
{
    const int n = blockIdx.x * 256 + threadIdx.x;
    const bool valid = (n < N);
    float x[6];
#pragma unroll
    for (int k = 0; k < 6; ++k) x[k] = valid ? X[n * 6 + k] : 0.0f;
    float enc[ENC_DIM];
#pragma unroll
    for (int d = 0; d < 6; ++d)
#pragma unroll
        for (int f = 0; f < 6; ++f) {
            float s, c;
            __sincosf(x[d] * (float)(1 << f), &s, &c);
            enc[d * 12 + f] = s; enc[d * 12 + 6 + f] = c;
        }
    float acc0 = 0, acc1 = 0, acc2 = 0, denom = 0;
#pragma unroll 1
    for (int c = 0; c < NCLUST; ++c) {
        float s = fmaf(x[0], cent[c*3], fmaf(x[1], cent[c*3+1], x[2]*cent[c*3+2]));
        float ew = __expf(s);
        const float* w = W + c * (3 * ENC_DIM);
        float d0 = 0, d1 = 0, d2 = 0;
#pragma unroll
        for (int e = 0; e < ENC_DIM; ++e) {
            float ee = enc[e];
            d0 = fmaf(ee, w[e], d0);
            d1 = fmaf(ee, w[ENC_DIM + e], d1);
            d2 = fmaf(ee, w[2 * ENC_DIM + e], d2);
        }
        denom += ew;
        acc0 = fmaf(ew, d0, acc0); acc1 = fmaf(ew, d1, acc1); acc2 = fmaf(ew, d2, acc2);
    }
    if (valid) {
        float inv = 1.0f / denom;
        out[n*3+0] = acc0*inv; out[n*3+1] = acc1*inv; out[n*3+2] = acc2*inv;
    }
}

extern "C" void kernel_launch(void* const* d_in, const int* in_sizes, int n_in,
                              void* d_out, int out_size, void* d_ws, size_t ws_size,
                              hipStream_t stream)
{
    const float* X    = (const float*)d_in[0];   // [N, 6]
    const float* W    = (const float*)d_in[1];   // [768, 72]
    const float* cent = (const float*)d_in[2];   // [256, 3]
    float* out = (float*)d_out;                  // [N, 3]
    const int N = in_sizes[0] / 6;

    if (ws_size >= (size_t)BG_BYTES) {
        unsigned short* Bg = (unsigned short*)d_ws;
        prep_kernel<<<NJ_PAD, NCLUST, 0, stream>>>(W, Bg);
        const int blocks = (N + M_BLK - 1) / M_BLK;
        rgb_attn_mfma<<<blocks, THREADS, 0, stream>>>(X, cent, Bg, out, N);
    } else {
        rgb_attn_fallback<<<(N + 255) / 256, 256, 0, stream>>>(X, W, cent, out, N);
    }
}